// Round 11
// baseline (966.325 us; speedup 1.0000x reference)
//
#include <hip/hip_runtime.h>

#define DEVFN __device__ __forceinline__

typedef _Float16 f16;
typedef _Float16 f16x8 __attribute__((ext_vector_type(8)));
typedef _Float16 f16x4 __attribute__((ext_vector_type(4)));
typedef _Float16 f16x2 __attribute__((ext_vector_type(2)));
typedef float    f32x4 __attribute__((ext_vector_type(4)));

enum { NB = 32, NS = 512, ND = 512, NH = 16, NK = 32, NA = 256 };

#define SZ(x) ((size_t)(x))

// ---- async global->LDS (16B per lane; per-lane LDS addr must be wave-base + lane*16) ----
typedef __attribute__((address_space(3))) void       as3_void;
typedef const __attribute__((address_space(1))) void as1_cvoid;
DEVFN void ldsdma16(const void* g, void* l) {
  __builtin_amdgcn_global_load_lds((as1_cvoid*)g, (as3_void*)l, 16, 0, 0);
}

// XCD-chunked bijective block swizzle (grid size must be %8==0)
DEVFN int xcd_swz(int flat, int n) {
  return (flat & 7) * (n >> 3) + (flat >> 3);
}

// =====================================================================
// 256x512 NT fp16 GEMM "dual" core — 16 virtual K-tiles (BK=64):
//   half hB = vt>>3 selects B panel (Bg + hB*256*ldb);
//   acc[8][4] covers 256x256; epi(hB, acc) dumps it after vt=7 and vt=15.
// 512 threads = 8 waves (2M x 4N); per-wave output 128x64.
// LDS: 2 dbuf x (A 256x64 + B 256x64) = 128 KB; quadrant staging;
// counted vmcnt(6) once per tile (3 half-units in flight); barriers per
// phase but NO sched_barrier / NO asm lgkm (m141: pinning regresses —
// compiler handles ds_read->MFMA waits from SSA deps).
// launch_bounds (512,2): (512,4) spills the 128-reg accumulator
// (measured r8: WRITE_SIZE 65MB -> 1GB, 5x slower). Do not raise.
// =====================================================================
template <class EPI>
DEVFN void gemm256x2(const f16* __restrict__ Ag, const f16* __restrict__ Bg,
                     int lda, int ldb, f16* smem, EPI epi) {
  const int tid  = threadIdx.x;      // 0..511
  const int lane = tid & 63;
  const int wid  = tid >> 6;         // 0..7
  const int wr   = wid >> 2;         // 0..1  (M half)
  const int wcn  = wid & 3;          // 0..3  (N quarter)
  const int s_r  = tid >> 3;         // staging row-within-group 0..63
  const int s_g  = tid & 7;          // staging granule 0..7 (rows are 128B)
  const int frow = lane & 15;
  const int fg   = lane >> 4;        // k-granule 0..3 within a 64B k-half

  f32x4 acc[8][4] = {};

  auto stageA = [&](int vt, int h) {  // A-Qh: rows j*128 + h*64 + s_r
    f16* base = smem + (vt & 1) * 32768;
    const f16* G = Ag + (vt & 7) * 64;
#pragma unroll
    for (int j = 0; j < 2; ++j) {
      int row = j * 128 + h * 64 + s_r;
      ldsdma16(G + SZ(row) * lda + ((s_g ^ (row & 7)) * 8), base + row * 64 + s_g * 8);
    }
  };
  auto stageB = [&](int vt, int h) {
    f16* base = smem + (vt & 1) * 32768 + 16384;
    const f16* G = Bg + SZ(vt >> 3) * 256 * ldb + (vt & 7) * 64;
#pragma unroll
    for (int j = 0; j < 2; ++j) {
      int row = (j * 2 + (s_r >> 5)) * 64 + h * 32 + (s_r & 31);
      ldsdma16(G + SZ(row) * ldb + ((s_g ^ (row & 7)) * 8), base + row * 64 + s_g * 8);
    }
  };
  auto rdA = [&](int vt, int row, int kk) -> f16x8 {
    const f16* base = smem + (vt & 1) * 32768;
    return *(const f16x8*)(base + row * 64 + (((kk * 4 + fg) ^ (row & 7)) * 8));
  };
  auto rdB = [&](int vt, int row, int kk) -> f16x8 {
    const f16* base = smem + (vt & 1) * 32768 + 16384;
    return *(const f16x8*)(base + row * 64 + (((kk * 4 + fg) ^ (row & 7)) * 8));
  };

  f16x8 af[8], bf0[4], bf1[4];

#define QUAD(a, b, BF)                                                          \
  _Pragma("unroll")                                                             \
  for (int mi = 0; mi < 4; ++mi)                                                \
    _Pragma("unroll")                                                           \
    for (int ni = 0; ni < 2; ++ni)                                              \
      _Pragma("unroll")                                                         \
      for (int kk = 0; kk < 2; ++kk)                                            \
        acc[(a)*4 + mi][(b)*2 + ni] = __builtin_amdgcn_mfma_f32_16x16x32_f16(   \
            af[mi * 2 + kk], BF[ni * 2 + kk], acc[(a)*4 + mi][(b)*2 + ni], 0, 0, 0);

#define MFMA_PHASE(MB)                   \
  __builtin_amdgcn_s_barrier();          \
  __builtin_amdgcn_s_setprio(1);         \
  MB                                     \
  __builtin_amdgcn_s_setprio(0);

  // prologue: vt0 fully (4 units), vt1 minus A-Q1 (3 units) = 14 loads/thread-slot
  stageA(0, 0); stageB(0, 0); stageB(0, 1); stageA(0, 1);
  stageA(1, 0); stageB(1, 0); stageB(1, 1);
  asm volatile("s_waitcnt vmcnt(6)" ::: "memory");  // vt0's 8 landed
  __builtin_amdgcn_s_barrier();

  for (int vt = 0; vt < 16; ++vt) {
    // ---- P0: Q(0,0) ----
#pragma unroll
    for (int mi = 0; mi < 4; ++mi)
#pragma unroll
      for (int kk = 0; kk < 2; ++kk)
        af[mi * 2 + kk] = rdA(vt, wr * 128 + mi * 16 + frow, kk);
#pragma unroll
    for (int ni = 0; ni < 2; ++ni)
#pragma unroll
      for (int kk = 0; kk < 2; ++kk)
        bf0[ni * 2 + kk] = rdB(vt, wcn * 64 + ni * 16 + frow, kk);
    if (vt <= 14) stageA(vt + 1, 1);
    MFMA_PHASE(QUAD(0, 0, bf0))
    __builtin_amdgcn_s_barrier();  // all waves done reading A-Q0/B-Q0 -> P1/P2 stages may overwrite

    // ---- P1: Q(0,1) ----
#pragma unroll
    for (int ni = 0; ni < 2; ++ni)
#pragma unroll
      for (int kk = 0; kk < 2; ++kk)
        bf1[ni * 2 + kk] = rdB(vt, wcn * 64 + 32 + ni * 16 + frow, kk);
    if (vt <= 13) stageA(vt + 2, 0);
    MFMA_PHASE(QUAD(0, 1, bf1))
    __builtin_amdgcn_s_barrier();  // B-Q1 reads done -> P3's stage may overwrite

    // ---- P2: Q(1,1) ----
#pragma unroll
    for (int mi = 0; mi < 4; ++mi)
#pragma unroll
      for (int kk = 0; kk < 2; ++kk)
        af[mi * 2 + kk] = rdA(vt, wr * 128 + 64 + mi * 16 + frow, kk);
    if (vt <= 13) stageB(vt + 2, 0);
    MFMA_PHASE(QUAD(1, 1, bf1))
    __builtin_amdgcn_s_barrier();

    // ---- P3: Q(1,0) (A from P2, B from P0 — in regs) ----
    if (vt <= 13) stageB(vt + 2, 1);
    MFMA_PHASE(QUAD(1, 0, bf0))
    if (vt <= 13)      asm volatile("s_waitcnt vmcnt(6)" ::: "memory");  // vt+1 landed
    else if (vt == 14) asm volatile("s_waitcnt vmcnt(0)" ::: "memory");  // vt15 landed
    __builtin_amdgcn_s_barrier();

    if (vt == 7) {
      epi(0, acc);  // dump first 256x256 half (contains its own __syncthreads if needed)
#pragma unroll
      for (int mi = 0; mi < 8; ++mi)
#pragma unroll
        for (int ni = 0; ni < 4; ++ni) acc[mi][ni] = f32x4{0.f, 0.f, 0.f, 0.f};
    }
  }
  epi(1, acc);
#undef QUAD
#undef MFMA_PHASE
}

// =====================================================================
// Legacy 128x128 NT fp16 GEMM core (kept for small GEMMs)
// =====================================================================
DEVFN void gemm_core_128(const f16* __restrict__ Ag, const f16* __restrict__ Bg,
                         int lda, int ldb, int nk, f16* lds, f32x4 acc[4][4]) {
  f16* As = lds;
  f16* Bs = lds + 128 * 64;
  const int tid  = threadIdx.x;
  const int lane = tid & 63;
  const int wvid = tid >> 6, wr = wvid >> 1, wc = wvid & 1;
  const int srow = tid >> 3, scol = (tid & 7) * 8;
  const int frow = lane & 15, fk = (lane >> 4) * 8;
  for (int ks = 0; ks < nk; ++ks) {
    const f16* ga = Ag + ks * 64 + scol;
    const f16* gb = Bg + ks * 64 + scol;
#pragma unroll
    for (int r = 0; r < 4; ++r) {
      ldsdma16(ga + SZ(r * 32 + srow) * lda, As + SZ(r * 32 + srow) * 64 + scol);
      ldsdma16(gb + SZ(r * 32 + srow) * ldb, Bs + SZ(r * 32 + srow) * 64 + scol);
    }
    __syncthreads();
#pragma unroll
    for (int kk = 0; kk < 64; kk += 32) {
      f16x8 a[4], b[4];
#pragma unroll
      for (int i = 0; i < 4; ++i)
        a[i] = *(const f16x8*)(As + SZ(wr * 64 + i * 16 + frow) * 64 + kk + fk);
#pragma unroll
      for (int j = 0; j < 4; ++j)
        b[j] = *(const f16x8*)(Bs + SZ(wc * 64 + j * 16 + frow) * 64 + kk + fk);
#pragma unroll
      for (int i = 0; i < 4; ++i)
#pragma unroll
        for (int j = 0; j < 4; ++j)
          acc[i][j] = __builtin_amdgcn_mfma_f32_16x16x32_f16(a[i], b[j], acc[i][j], 0, 0, 0);
    }
    __syncthreads();
  }
}
// C/D frag mapping (16x16x32): col = lane&15, row = (lane>>4)*4 + reg.

// ---- swizzled LDS helpers for [128][128] f16 weight tile (row stride 256 B) ----
DEVFN void wlds_write(f16* wlds, int row, int col, f16 v) {
  int byte = (row * 256 + col * 2) ^ ((row & 7) << 4);
  *(f16*)((char*)wlds + byte) = v;
}
DEVFN f16x8 wlds_read8(const f16* wlds, int row, int col) {
  int byte = (row * 256 + col * 2) ^ ((row & 7) << 4);
  return *(const f16x8*)((const char*)wlds + byte);
}

// ---- prep kernels ----
__global__ __launch_bounds__(256) void k_cast4(const float* __restrict__ s,
                                               f16* __restrict__ d, int n4) {
  int i = blockIdx.x * 256 + threadIdx.x;
  if (i >= n4) return;
  float4 v = ((const float4*)s)[i];
  f16x4 o; o[0] = (f16)v.x; o[1] = (f16)v.y; o[2] = (f16)v.z; o[3] = (f16)v.w;
  ((f16x4*)d)[i] = o;
}

__global__ void k_tcast(const float* __restrict__ src, f16* __restrict__ dst,
                        int R, int C, long sStride, long dStride) {
  __shared__ float tile[32][33];
  src += (long)blockIdx.z * sStride;
  dst += (long)blockIdx.z * dStride;
  int c0 = blockIdx.x * 32, r0 = blockIdx.y * 32;
  int tx = threadIdx.x, ty = threadIdx.y;
#pragma unroll
  for (int i = 0; i < 4; ++i)
    tile[ty + 8 * i][tx] = src[(long)(r0 + ty + 8 * i) * C + c0 + tx];
  __syncthreads();
#pragma unroll
  for (int i = 0; i < 4; ++i)
    dst[(long)(c0 + ty + 8 * i) * R + r0 + tx] = (f16)tile[tx][ty + 8 * i];
}

// ---- xv^T (legacy core) ----
__global__ __launch_bounds__(256) void k_gemm_xv(const f16* __restrict__ xh,
                                                 const f16* __restrict__ vwt,
                                                 f16* __restrict__ xvt) {
  __shared__ f16 smem[128 * 64 * 2];
  int z = blockIdx.z, b = z >> 2, hg = z & 3, tm = blockIdx.x;
  f32x4 acc[4][4] = {};
  gemm_core_128(xh + SZ(b) * NS * ND + SZ(tm) * 128 * ND,
                vwt + SZ(hg) * 4 * NK * ND, ND, ND, ND / 64, smem, acc);
  int tid = threadIdx.x, lane = tid & 63, wvid = tid >> 6, wr = wvid >> 1, wc = wvid & 1;
  int rbase = (lane >> 4) * 4, cbase = lane & 15;
#pragma unroll
  for (int mi = 0; mi < 4; ++mi)
#pragma unroll
    for (int ni = 0; ni < 4; ++ni) {
      int n = wc * 64 + ni * 16 + cbase;
      int hh = hg * 4 + (n >> 5), kk = n & 31;
#pragma unroll
      for (int r = 0; r < 4; ++r) {
        int t = tm * 128 + wr * 64 + mi * 16 + rbase + r;
        xvt[(SZ(b * NH + hh) * NK + kk) * NS + t] = (f16)acc[mi][ni][r];
      }
    }
}

// ---- q = x @ Qw + Qb : 256x512 dual-half blocks ----
__global__ __launch_bounds__(512, 2) void k_gemm_q256(const f16* __restrict__ xh,
                                                      const f16* __restrict__ qwt,
                                                      const float* __restrict__ Qb,
                                                      f16* __restrict__ qc, int b0) {
  __shared__ f16 smem[65536];  // 128 KB: 2 dbuf x (A+B)
  int n = gridDim.x;
  int lg = xcd_swz(blockIdx.x, n);
  int tm2 = lg & 1, bhl = lg >> 1;
  int b = b0 + (bhl >> 4), h = bhl & 15;
  int lane = threadIdx.x & 63, wid = threadIdx.x >> 6;
  int wr = wid >> 2, wcn = wid & 3;
  int rbase = (lane >> 4) * 4, cbase = lane & 15;
  f16* qb = qc + SZ(bhl) * NS * ND;
  auto epi = [&](int hB, f32x4 (&acc)[8][4]) {
#pragma unroll
    for (int mi = 0; mi < 8; ++mi)
#pragma unroll
      for (int ni = 0; ni < 4; ++ni) {
        int colg = hB * 256 + wcn * 64 + ni * 16 + cbase;
        float bias = Qb[h * ND + colg];
#pragma unroll
        for (int r = 0; r < 4; ++r) {
          int rowg = tm2 * 256 + wr * 128 + mi * 16 + rbase + r;
          qb[SZ(rowg) * ND + colg] = (f16)(acc[mi][ni][r] + bias);
        }
      }
  };
  gemm256x2(xh + SZ(b) * NS * ND + SZ(tm2) * 256 * ND,
            qwt + SZ(h) * ND * ND, ND, ND, smem, epi);
}

// ---- scores 256x512 dual-half: store E=exp(s - blk_colmax) + per-key stats ----
// sc block index: lg = bhl*4 + tt2*2 + st2; per-block layout:
//   f16x4 at ((wid*8+mi)*4+ni)*64 + lane
__global__ __launch_bounds__(512, 2) void k_scores256(const f16* __restrict__ qc,
                                                      const f16* __restrict__ xh,
                                                      f16* __restrict__ sc,
                                                      float* __restrict__ mp,
                                                      float* __restrict__ zp, int b0) {
  __shared__ f16 smem[65536];
  __shared__ float sbuf[1024];  // dedicated stats buffer (staging continues in-flight)
  int n = gridDim.x;
  int lg = xcd_swz(blockIdx.x, n);
  int st2 = lg & 1, bhl = lg >> 1;
  int b = b0 + (bhl >> 4);
  int tid = threadIdx.x, lane = tid & 63, wid = tid >> 6;
  int wr = wid >> 2, wcn = wid & 3;
  auto epi = [&](int hB, f32x4 (&acc)[8][4]) {
    __syncthreads();  // prior epi's sbuf reads done before overwrite
    // 1) per-wave (128-row) column max
    float mh[4];
#pragma unroll
    for (int ni = 0; ni < 4; ++ni) {
      float m = -1e30f;
#pragma unroll
      for (int mi = 0; mi < 8; ++mi)
#pragma unroll
        for (int r = 0; r < 4; ++r) m = fmaxf(m, acc[mi][ni][r]);
      m = fmaxf(m, __shfl_xor(m, 16));
      m = fmaxf(m, __shfl_xor(m, 32));  // lanes {l,l^16,l^32,l^48} share col
      mh[ni] = m;
    }
    if (lane < 16) {
#pragma unroll
      for (int ni = 0; ni < 4; ++ni)
        sbuf[wr * 256 + wcn * 64 + ni * 16 + lane] = mh[ni];
    }
    __syncthreads();
    // 2) block (256-row) column max
    int cb_ = lane & 15;
    float tmc[4];
#pragma unroll
    for (int ni = 0; ni < 4; ++ni) {
      int col = wcn * 64 + ni * 16 + cb_;
      tmc[ni] = fmaxf(sbuf[col], sbuf[256 + col]);
    }
    // 3) store E and accumulate column sums
    int lgE = bhl * 4 + hB * 2 + st2;
    f16x4* scb = (f16x4*)(sc + SZ(lgE) * 65536);
    float sm[4] = {0.f, 0.f, 0.f, 0.f};
#pragma unroll
    for (int mi = 0; mi < 8; ++mi)
#pragma unroll
      for (int ni = 0; ni < 4; ++ni) {
        f16x4 o;
#pragma unroll
        for (int r = 0; r < 4; ++r) {
          float ev = __expf(acc[mi][ni][r] - tmc[ni]);
          o[r] = (f16)ev;
          sm[ni] += ev;
        }
        scb[((wid * 8 + mi) * 4 + ni) * 64 + lane] = o;
      }
#pragma unroll
    for (int ni = 0; ni < 4; ++ni) {
      sm[ni] += __shfl_xor(sm[ni], 16);
      sm[ni] += __shfl_xor(sm[ni], 32);
    }
    if (lane < 16) {
#pragma unroll
      for (int ni = 0; ni < 4; ++ni)
        sbuf[512 + wr * 256 + wcn * 64 + ni * 16 + lane] = sm[ni];
    }
    __syncthreads();
    // 4) per-block stats (both wr halves shifted by same tmc -> plain add)
    if (tid < 256) {
      float m  = fmaxf(sbuf[tid], sbuf[256 + tid]);
      float zz = sbuf[512 + tid] + sbuf[768 + tid];
      size_t idx = (SZ(bhl) * 2 + st2) * NS + hB * 256 + tid;
      mp[idx] = m; zp[idx] = zz;
    }
  };
  gemm256x2(qc + SZ(bhl) * NS * ND + SZ(st2) * 256 * ND,
            xh + SZ(b) * NS * ND, ND, ND, smem, epi);
}

// ---- combine: per (bhl, t): cs[st2] = exp(mp[st2]-m)/Z ----
__global__ __launch_bounds__(256) void k_stats_combine(const float* __restrict__ mp,
                                                       const float* __restrict__ zp,
                                                       float* __restrict__ cs) {
  int i = blockIdx.x * 256 + threadIdx.x;  // cb*NH*NS
  int bhl = i >> 9, t = i & (NS - 1);
  float m0 = mp[(SZ(bhl) * 2 + 0) * NS + t];
  float m1 = mp[(SZ(bhl) * 2 + 1) * NS + t];
  float m = fmaxf(m0, m1);
  float e0 = __expf(m0 - m), e1 = __expf(m1 - m);
  float Z = zp[(SZ(bhl) * 2 + 0) * NS + t] * e0 + zp[(SZ(bhl) * 2 + 1) * NS + t] * e1;
  float rZ = 1.0f / Z;
  cs[(SZ(bhl) * 2 + 0) * NS + t] = e0 * rZ;
  cs[(SZ(bhl) * 2 + 1) * NS + t] = e1 * rZ;
}

// ---- weight stored E by per-column scale + PV ----
__global__ __launch_bounds__(256) void k_norm_pv(const f16* __restrict__ sc,
                                                 const f16* __restrict__ xvt,
                                                 const float* __restrict__ cs,
                                                 const float* __restrict__ Vb,
                                                 f16* __restrict__ h16, int b0) {
  __shared__ f16 wlds[128 * 128];  // 32 KB, XOR-swizzled
  int bhl = blockIdx.y, b = b0 + (bhl >> 4), h = bhl & 15;
  int st = blockIdx.x;  // 128-row strip 0..3
  int tid = threadIdx.x, lane = tid & 63, wvid = tid >> 6, wr = wvid >> 1, wc = wvid & 1;
  int rbase = (lane >> 4) * 4, cbase = lane & 15, fk = (lane >> 4) * 8;
  f32x4 acc2[2][2] = {};
  const f16* xvh = xvt + SZ(b * NH + h) * NK * NS;
  for (int tt = 0; tt < 4; ++tt) {
    // E source block: producer stored at lg = bhl*4 + tt2*2 + st2
    int blk = (bhl * 2 + (tt >> 1)) * 2 + (st >> 1);
    const f16x4* scb = (const f16x4*)(sc + SZ(blk) * 65536);
    int wave_sc = (st & 1) * 4 + ((tt & 1) * 2 + wc);
#pragma unroll
    for (int ni = 0; ni < 4; ++ni) {
      int tl = wc * 64 + ni * 16 + cbase;
      float csv = cs[(SZ(bhl) * 2 + (st >> 1)) * NS + tt * 128 + tl];
#pragma unroll
      for (int mi = 0; mi < 4; ++mi) {
        int mi_sc = wr * 4 + mi;
        f16x4 v = scb[((wave_sc * 8 + mi_sc) * 4 + ni) * 64 + lane];
#pragma unroll
        for (int r = 0; r < 4; ++r) {
          int sl = wr * 64 + mi * 16 + rbase + r;
          wlds_write(wlds, sl, tl, (f16)((float)v[r] * csv));
        }
      }
    }
    __syncthreads();
    const f16* xvb = xvh + tt * 128;
#pragma unroll
    for (int tc = 0; tc < 4; ++tc) {
      f16x8 aw[2], bx[2];
#pragma unroll
      for (int m2 = 0; m2 < 2; ++m2)
        aw[m2] = wlds_read8(wlds, wvid * 32 + m2 * 16 + cbase, tc * 32 + fk);
#pragma unroll
      for (int n2 = 0; n2 < 2; ++n2)
        bx[n2] = *(const f16x8*)(xvb + SZ(n2 * 16 + cbase) * NS + tc * 32 + fk);
#pragma unroll
      for (int m2 = 0; m2 < 2; ++m2)
#pragma unroll
        for (int n2 = 0; n2 < 2; ++n2)
          acc2[m2][n2] = __builtin_amdgcn_mfma_f32_16x16x32_f16(aw[m2], bx[n2], acc2[m2][n2], 0, 0, 0);
    }
    __syncthreads();
  }
  const float* vb = Vb + h * NK;
#pragma unroll
  for (int m2 = 0; m2 < 2; ++m2)
#pragma unroll
    for (int n2 = 0; n2 < 2; ++n2)
#pragma unroll
      for (int r = 0; r < 4; ++r) {
        int sg = st * 128 + wvid * 32 + m2 * 16 + rbase + r;
        int kk = n2 * 16 + cbase;
        float val = acc2[m2][n2][r] + vb[kk];
        h16[SZ(b * NS + sg) * (NH * NK) + h * NK + kk] = (f16)val;
      }
}

// ---- U = tanh(h @ Wv + bv), stored f16 ----
__global__ __launch_bounds__(256) void k_gemm_u(const f16* __restrict__ h16,
                                                const f16* __restrict__ wvt,
                                                const float* __restrict__ bv,
                                                f16* __restrict__ U) {
  __shared__ f16 smem[128 * 64 * 2];
  int tm = blockIdx.x, tn = blockIdx.y;
  f32x4 acc[4][4] = {};
  gemm_core_128(h16 + SZ(tm) * 128 * ND, wvt + SZ(tn) * 128 * ND, ND, ND, ND / 64, smem, acc);
  int tid = threadIdx.x, lane = tid & 63, wvid = tid >> 6, wr = wvid >> 1, wc = wvid & 1;
  int rbase = (lane >> 4) * 4, cbase = lane & 15;
#pragma unroll
  for (int mi = 0; mi < 4; ++mi)
#pragma unroll
    for (int ni = 0; ni < 4; ++ni) {
      int colg = tn * 128 + wc * 64 + ni * 16 + cbase;
      float bias = bv[colg];
#pragma unroll
      for (int r = 0; r < 4; ++r) {
        int rowg = tm * 128 + wr * 64 + mi * 16 + rbase + r;
        U[SZ(rowg) * NA + colg] = (f16)tanhf(acc[mi][ni][r] + bias);
      }
    }
}

// ---- a = U @ wq + bq (one wave per row) ----
__global__ __launch_bounds__(256) void k_a(const f16* __restrict__ U,
                                           const float* __restrict__ wq,
                                           const float* __restrict__ bq,
                                           float* __restrict__ a) {
  int wid = (blockIdx.x * 256 + threadIdx.x) >> 6;
  int lane = threadIdx.x & 63;
  const f16* u = U + SZ(wid) * NA;
  float p = 0.f;
#pragma unroll
  for (int j = 0; j < NA / 64; ++j) p += (float)u[lane + 64 * j] * wq[lane + 64 * j];
#pragma unroll
  for (int o = 32; o; o >>= 1) p += __shfl_xor(p, o);
  if (lane == 0) a[wid] = p + bq[0];
}

// ---- z partials ----
__global__ __launch_bounds__(256) void k_zpart(const f16* __restrict__ h16,
                                               const float* __restrict__ a,
                                               float* __restrict__ zpt) {
  int b = blockIdx.y, c = blockIdx.x, tid = threadIdx.x;
  float z0 = 0.f, z1 = 0.f;
  for (int s = 0; s < 64; ++s) {
    int sg = c * 64 + s;
    float av = a[b * NS + sg];
    const f16* hr = h16 + SZ(b * NS + sg) * (NH * NK);
    f16x2 v = ((const f16x2*)hr)[tid];
    z0 += av * (float)v[0];
    z1 += av * (float)v[1];
  }
  zpt[SZ(b * 8 + c) * 512 + 2 * tid]     = z0;
  zpt[SZ(b * 8 + c) * 512 + 2 * tid + 1] = z1;
}

__global__ __launch_bounds__(256) void k_zred(const float* __restrict__ zpt,
                                              float* __restrict__ out) {
  int i = blockIdx.x * 256 + threadIdx.x;  // NB*512
  int b = i >> 9, k = i & 511;
  float z = 0.f;
#pragma unroll
  for (int c = 0; c < 8; ++c) z += zpt[SZ(b * 8 + c) * 512 + k];
  out[i] = z;
}

// ---- workspace layout as a function of chunk size cb ----
static size_t ws_plan(int cb, size_t off[14]) {
  size_t o = 0;
  auto put = [&](size_t bytes) { size_t r = o; o += (bytes + 255) & ~SZ(255); return r; };
  off[0]  = put(SZ(NB) * NS * ND * 2);       // xh
  off[1]  = put(SZ(NH) * ND * ND * 2);       // qwt
  off[2]  = put(SZ(NA) * ND * 2);            // wvt
  off[3]  = put(SZ(NH) * NK * ND * 2);       // vwt
  off[4]  = put(SZ(NB) * NH * NK * NS * 2);  // xvt
  off[5]  = put(SZ(cb) * NH * NS * ND * 2);  // qc
  off[6]  = put(SZ(cb) * NH * NS * NS * 2);  // sc (E values, frag-blocked)
  off[7]  = put(SZ(cb) * NH * 2 * NS * 4);   // mp
  off[8]  = put(SZ(cb) * NH * 2 * NS * 4);   // zps
  off[9]  = put(SZ(cb) * NH * 2 * NS * 4);   // cs
  off[10] = put(SZ(NB) * NS * NH * NK * 2);  // h16
  off[11] = put(SZ(NB) * NS * NA * 2);       // U
  off[12] = put(SZ(NB) * NS * 4);            // a
  off[13] = put(SZ(NB) * 8 * NH * NK * 4);   // zpt
  return o;
}

extern "C" void kernel_launch(void* const* d_in, const int* in_sizes, int n_in,
                              void* d_out, int out_size, void* d_ws, size_t ws_size,
                              hipStream_t stream) {
  const float* x  = (const float*)d_in[0];
  const float* Qw = (const float*)d_in[1];
  const float* Qb = (const float*)d_in[2];
  const float* Vw = (const float*)d_in[3];
  const float* Vb = (const float*)d_in[4];
  const float* Wv = (const float*)d_in[5];
  const float* bv = (const float*)d_in[6];
  const float* wq = (const float*)d_in[7];
  const float* bq = (const float*)d_in[8];

  int cbv = 0;
  size_t off[14];
  const int cand[5] = {32, 16, 8, 4, 2};
  for (int ci = 0; ci < 5; ++ci) {
    if (ws_plan(cand[ci], off) <= ws_size) { cbv = cand[ci]; break; }
  }
  if (cbv == 0) return;

  char* ws = (char*)d_ws;
  f16*   xh   = (f16*)(ws + off[0]);
  f16*   qwt  = (f16*)(ws + off[1]);
  f16*   wvt  = (f16*)(ws + off[2]);
  f16*   vwt  = (f16*)(ws + off[3]);
  f16*   xvt  = (f16*)(ws + off[4]);
  f16*   qc   = (f16*)(ws + off[5]);
  f16*   sc   = (f16*)(ws + off[6]);
  float* mp   = (float*)(ws + off[7]);
  float* zps  = (float*)(ws + off[8]);
  float* cs   = (float*)(ws + off[9]);
  f16*   h16  = (f16*)(ws + off[10]);
  f16*   U    = (f16*)(ws + off[11]);
  float* a    = (float*)(ws + off[12]);
  float* zpt  = (float*)(ws + off[13]);
  float* zout = (float*)d_out;

  // prep
  k_cast4<<<SZ(NB) * NS * ND / 4 / 256, 256, 0, stream>>>(x, xh, NB * NS * ND / 4);
  k_tcast<<<dim3(16, 16, 16), dim3(32, 8), 0, stream>>>(Qw, qwt, ND, ND, (long)ND * ND, (long)ND * ND);
  k_tcast<<<dim3(8, 16, 1), dim3(32, 8), 0, stream>>>(Wv, wvt, ND, NA, 0, 0);
  k_tcast<<<dim3(1, 16, 16), dim3(32, 8), 0, stream>>>(Vw, vwt, ND, NK, (long)ND * NK, (long)NK * ND);
  k_gemm_xv<<<dim3(4, 1, NB * 4), 256, 0, stream>>>(xh, vwt, xvt);

  // batch-chunked attention: q -> E+stats -> combine -> weight+PV
  for (int b0 = 0; b0 < NB; b0 += cbv) {
    k_gemm_q256<<<cbv * 32, 512, 0, stream>>>(xh, qwt, Qb, qc, b0);
    k_scores256<<<cbv * 32, 512, 0, stream>>>(qc, xh, sc, mp, zps, b0);
    k_stats_combine<<<cbv * NH * NS / 256, 256, 0, stream>>>(mp, zps, cs);
    k_norm_pv<<<dim3(4, cbv * NH), 256, 0, stream>>>(sc, xvt, cs, Vb, h16, b0);
  }

  // pooling
  k_gemm_u<<<dim3(NB * NS / 128, 2, 1), 256, 0, stream>>>(h16, wvt, bv, U);
  k_a<<<NB * NS / 4, 256, 0, stream>>>(U, wq, bq, a);
  k_zpart<<<dim3(8, NB), 256, 0, stream>>>(h16, a, zpt);
  k_zred<<<NB * 512 / 256, 256, 0, stream>>>(zpt, zout);
}

// Round 12
// 507.716 us; speedup vs baseline: 1.9033x; 1.9033x over previous
//
#include <hip/hip_runtime.h>

#define DEVFN __device__ __forceinline__

typedef _Float16 f16;
typedef _Float16 f16x8 __attribute__((ext_vector_type(8)));
typedef _Float16 f16x4 __attribute__((ext_vector_type(4)));
typedef _Float16 f16x2 __attribute__((ext_vector_type(2)));
typedef float    f32x4 __attribute__((ext_vector_type(4)));

enum { NB = 32, NS = 512, ND = 512, NH = 16, NK = 32, NA = 256 };

#define SZ(x) ((size_t)(x))

// ---- async global->LDS (16B per lane; per-lane LDS addr must be wave-base + lane*16) ----
typedef __attribute__((address_space(3))) void       as3_void;
typedef const __attribute__((address_space(1))) void as1_cvoid;
DEVFN void ldsdma16(const void* g, void* l) {
  __builtin_amdgcn_global_load_lds((as1_cvoid*)g, (as3_void*)l, 16, 0, 0);
}

// XCD-chunked bijective block swizzle (grid size must be %8==0)
DEVFN int xcd_swz(int flat, int n) {
  return (flat & 7) * (n >> 3) + (flat >> 3);
}

// =====================================================================
// 256x256 NT fp16 GEMM core — 4-phase quadrant schedule (round-10 base):
//   acc[8][4] += A[256 x 512] * B[256 x 512]^T   (K = 512, BK = 64)
// 512 threads = 8 waves (2M x 4N); per-wave output 128x64.
// LDS: 2 dbuf x (A 256x64 + B 256x64) = 128 KB; granule-XOR swizzle
// (bank-conflict-free, measured: SQ_LDS_BANK_CONFLICT 3.1M -> 0).
// Counted vmcnt(6) once per tile (3 half-units in flight).
// CHANGE vs r10: no lgkmcnt(0) asm / no sched_barrier(0) in phase tails —
// deps are SSA-visible (plain C++ ds_reads feed MFMA intrinsics, consumed
// within their own phase), so compiler inserts exact waits; m141 showed
// order-pinning regresses. vmcnt asm stays (global_load_lds->LDS hazards
// are compiler-invisible).
// launch_bounds (512,2): (512,4) spills the 128-reg accumulator
// (measured r8: WRITE_SIZE 65MB -> 1GB, 5x slower). Do not raise.
// =====================================================================
DEVFN void gemm256_pipe(const f16* __restrict__ Ag, const f16* __restrict__ Bg,
                        int lda, int ldb, f16* smem, f32x4 acc[8][4]) {
  const int tid  = threadIdx.x;      // 0..511
  const int lane = tid & 63;
  const int wid  = tid >> 6;         // 0..7
  const int wr   = wid >> 2;         // 0..1  (M half)
  const int wcn  = wid & 3;          // 0..3  (N quarter)
  const int s_r  = tid >> 3;         // staging row-within-group 0..63
  const int s_g  = tid & 7;          // staging granule 0..7 (rows are 128B)
  const int frow = lane & 15;
  const int fg   = lane >> 4;        // k-granule 0..3 within a 64B k-half

  auto stageA = [&](int t, int h) {  // A-Qh: rows j*128 + h*64 + s_r
    f16* base = smem + (t & 1) * 32768;
    const f16* G = Ag + t * 64;
#pragma unroll
    for (int j = 0; j < 2; ++j) {
      int row = j * 128 + h * 64 + s_r;
      ldsdma16(G + SZ(row) * lda + ((s_g ^ (row & 7)) * 8), base + row * 64 + s_g * 8);
    }
  };
  auto stageB = [&](int t, int h) {  // B-Qh: rows (j*2 + s_r>>5)*64 + h*32 + (s_r&31)
    f16* base = smem + (t & 1) * 32768 + 16384;
    const f16* G = Bg + t * 64;
#pragma unroll
    for (int j = 0; j < 2; ++j) {
      int row = (j * 2 + (s_r >> 5)) * 64 + h * 32 + (s_r & 31);
      ldsdma16(G + SZ(row) * ldb + ((s_g ^ (row & 7)) * 8), base + row * 64 + s_g * 8);
    }
  };
  auto rdA = [&](int t, int row, int kk) -> f16x8 {
    const f16* base = smem + (t & 1) * 32768;
    return *(const f16x8*)(base + row * 64 + (((kk * 4 + fg) ^ (row & 7)) * 8));
  };
  auto rdB = [&](int t, int row, int kk) -> f16x8 {
    const f16* base = smem + (t & 1) * 32768 + 16384;
    return *(const f16x8*)(base + row * 64 + (((kk * 4 + fg) ^ (row & 7)) * 8));
  };

  f16x8 af[8], bf0[4], bf1[4];

#define QUAD(a, b, BF)                                                          \
  _Pragma("unroll")                                                             \
  for (int mi = 0; mi < 4; ++mi)                                                \
    _Pragma("unroll")                                                           \
    for (int ni = 0; ni < 2; ++ni)                                              \
      _Pragma("unroll")                                                         \
      for (int kk = 0; kk < 2; ++kk)                                            \
        acc[(a)*4 + mi][(b)*2 + ni] = __builtin_amdgcn_mfma_f32_16x16x32_f16(   \
            af[mi * 2 + kk], BF[ni * 2 + kk], acc[(a)*4 + mi][(b)*2 + ni], 0, 0, 0);

#define PHASE_TAIL(MFMA_BLOCK)                              \
  __builtin_amdgcn_s_barrier();                             \
  __builtin_amdgcn_s_setprio(1);                            \
  MFMA_BLOCK                                                \
  __builtin_amdgcn_s_setprio(0);

  // prologue: tile0 fully (4 units), tile1 minus A-Q1 (3 units)
  stageA(0, 0); stageB(0, 0); stageB(0, 1); stageA(0, 1);
  stageA(1, 0); stageB(1, 0); stageB(1, 1);
  asm volatile("s_waitcnt vmcnt(6)" ::: "memory");  // tile 0's 8 landed
  __builtin_amdgcn_s_barrier();

  for (int t = 0; t < 8; ++t) {
    // ---- P0: Q(0,0) ----
#pragma unroll
    for (int mi = 0; mi < 4; ++mi)
#pragma unroll
      for (int kk = 0; kk < 2; ++kk)
        af[mi * 2 + kk] = rdA(t, wr * 128 + mi * 16 + frow, kk);
#pragma unroll
    for (int ni = 0; ni < 2; ++ni)
#pragma unroll
      for (int kk = 0; kk < 2; ++kk)
        bf0[ni * 2 + kk] = rdB(t, wcn * 64 + ni * 16 + frow, kk);
    if (t <= 6) stageA(t + 1, 1);
    PHASE_TAIL(QUAD(0, 0, bf0))
    __builtin_amdgcn_s_barrier();  // all waves' Q0-reads done -> later stages may overwrite

    // ---- P1: Q(0,1) ----
#pragma unroll
    for (int ni = 0; ni < 2; ++ni)
#pragma unroll
      for (int kk = 0; kk < 2; ++kk)
        bf1[ni * 2 + kk] = rdB(t, wcn * 64 + 32 + ni * 16 + frow, kk);
    if (t <= 5) stageA(t + 2, 0);
    PHASE_TAIL(QUAD(0, 1, bf1))
    __builtin_amdgcn_s_barrier();

    // ---- P2: Q(1,1) ----
#pragma unroll
    for (int mi = 0; mi < 4; ++mi)
#pragma unroll
      for (int kk = 0; kk < 2; ++kk)
        af[mi * 2 + kk] = rdA(t, wr * 128 + 64 + mi * 16 + frow, kk);
    if (t <= 5) stageB(t + 2, 0);
    PHASE_TAIL(QUAD(1, 1, bf1))
    __builtin_amdgcn_s_barrier();

    // ---- P3: Q(1,0) (A from P2, B from P0 — in regs) ----
    if (t <= 5) stageB(t + 2, 1);
    PHASE_TAIL(QUAD(1, 0, bf0))
    if (t < 6)       asm volatile("s_waitcnt vmcnt(6)" ::: "memory");  // tile t+1 landed
    else if (t == 6) asm volatile("s_waitcnt vmcnt(0)" ::: "memory");  // tile 7 landed
    __builtin_amdgcn_s_barrier();
  }
#undef QUAD
#undef PHASE_TAIL
}

// =====================================================================
// Legacy 128x128 NT fp16 GEMM core (kept for small GEMMs)
// =====================================================================
DEVFN void gemm_core_128(const f16* __restrict__ Ag, const f16* __restrict__ Bg,
                         int lda, int ldb, int nk, f16* lds, f32x4 acc[4][4]) {
  f16* As = lds;
  f16* Bs = lds + 128 * 64;
  const int tid  = threadIdx.x;
  const int lane = tid & 63;
  const int wvid = tid >> 6, wr = wvid >> 1, wc = wvid & 1;
  const int srow = tid >> 3, scol = (tid & 7) * 8;
  const int frow = lane & 15, fk = (lane >> 4) * 8;
  for (int ks = 0; ks < nk; ++ks) {
    const f16* ga = Ag + ks * 64 + scol;
    const f16* gb = Bg + ks * 64 + scol;
#pragma unroll
    for (int r = 0; r < 4; ++r) {
      ldsdma16(ga + SZ(r * 32 + srow) * lda, As + SZ(r * 32 + srow) * 64 + scol);
      ldsdma16(gb + SZ(r * 32 + srow) * ldb, Bs + SZ(r * 32 + srow) * 64 + scol);
    }
    __syncthreads();
#pragma unroll
    for (int kk = 0; kk < 64; kk += 32) {
      f16x8 a[4], b[4];
#pragma unroll
      for (int i = 0; i < 4; ++i)
        a[i] = *(const f16x8*)(As + SZ(wr * 64 + i * 16 + frow) * 64 + kk + fk);
#pragma unroll
      for (int j = 0; j < 4; ++j)
        b[j] = *(const f16x8*)(Bs + SZ(wc * 64 + j * 16 + frow) * 64 + kk + fk);
#pragma unroll
      for (int i = 0; i < 4; ++i)
#pragma unroll
        for (int j = 0; j < 4; ++j)
          acc[i][j] = __builtin_amdgcn_mfma_f32_16x16x32_f16(a[i], b[j], acc[i][j], 0, 0, 0);
    }
    __syncthreads();
  }
}
// C/D frag mapping (16x16x32): col = lane&15, row = (lane>>4)*4 + reg.

// ---- swizzled LDS helpers for [128][128] f16 weight tile (row stride 256 B) ----
DEVFN void wlds_write(f16* wlds, int row, int col, f16 v) {
  int byte = (row * 256 + col * 2) ^ ((row & 7) << 4);
  *(f16*)((char*)wlds + byte) = v;
}
DEVFN f16x8 wlds_read8(const f16* wlds, int row, int col) {
  int byte = (row * 256 + col * 2) ^ ((row & 7) << 4);
  return *(const f16x8*)((const char*)wlds + byte);
}

// ---- prep kernels ----
__global__ __launch_bounds__(256) void k_cast4(const float* __restrict__ s,
                                               f16* __restrict__ d, int n4) {
  int i = blockIdx.x * 256 + threadIdx.x;
  if (i >= n4) return;
  float4 v = ((const float4*)s)[i];
  f16x4 o; o[0] = (f16)v.x; o[1] = (f16)v.y; o[2] = (f16)v.z; o[3] = (f16)v.w;
  ((f16x4*)d)[i] = o;
}

__global__ void k_tcast(const float* __restrict__ src, f16* __restrict__ dst,
                        int R, int C, long sStride, long dStride) {
  __shared__ float tile[32][33];
  src += (long)blockIdx.z * sStride;
  dst += (long)blockIdx.z * dStride;
  int c0 = blockIdx.x * 32, r0 = blockIdx.y * 32;
  int tx = threadIdx.x, ty = threadIdx.y;
#pragma unroll
  for (int i = 0; i < 4; ++i)
    tile[ty + 8 * i][tx] = src[(long)(r0 + ty + 8 * i) * C + c0 + tx];
  __syncthreads();
#pragma unroll
  for (int i = 0; i < 4; ++i)
    dst[(long)(c0 + ty + 8 * i) * R + r0 + tx] = (f16)tile[tx][ty + 8 * i];
}

// ---- xv^T (legacy core) ----
__global__ __launch_bounds__(256) void k_gemm_xv(const f16* __restrict__ xh,
                                                 const f16* __restrict__ vwt,
                                                 f16* __restrict__ xvt) {
  __shared__ f16 smem[128 * 64 * 2];
  int z = blockIdx.z, b = z >> 2, hg = z & 3, tm = blockIdx.x;
  f32x4 acc[4][4] = {};
  gemm_core_128(xh + SZ(b) * NS * ND + SZ(tm) * 128 * ND,
                vwt + SZ(hg) * 4 * NK * ND, ND, ND, ND / 64, smem, acc);
  int tid = threadIdx.x, lane = tid & 63, wvid = tid >> 6, wr = wvid >> 1, wc = wvid & 1;
  int rbase = (lane >> 4) * 4, cbase = lane & 15;
#pragma unroll
  for (int mi = 0; mi < 4; ++mi)
#pragma unroll
    for (int ni = 0; ni < 4; ++ni) {
      int n = wc * 64 + ni * 16 + cbase;
      int hh = hg * 4 + (n >> 5), kk = n & 31;
#pragma unroll
      for (int r = 0; r < 4; ++r) {
        int t = tm * 128 + wr * 64 + mi * 16 + rbase + r;
        xvt[(SZ(b * NH + hh) * NK + kk) * NS + t] = (f16)acc[mi][ni][r];
      }
    }
}

// ---- q = x @ Qw + Qb : 256^2 ----
__global__ __launch_bounds__(512, 2) void k_gemm_q256(const f16* __restrict__ xh,
                                                      const f16* __restrict__ qwt,
                                                      const float* __restrict__ Qb,
                                                      f16* __restrict__ qc, int b0) {
  __shared__ f16 smem[65536];  // 128 KB: 2 dbuf x (A+B)
  int n = gridDim.x;
  int lg = xcd_swz(blockIdx.x, n);
  int tm2 = lg & 1, tn2 = (lg >> 1) & 1, bhl = lg >> 2;
  int b = b0 + (bhl >> 4), h = bhl & 15;
  f32x4 acc[8][4] = {};
  gemm256_pipe(xh + SZ(b) * NS * ND + SZ(tm2) * 256 * ND,
               qwt + SZ(h) * ND * ND + SZ(tn2) * 256 * ND, ND, ND, smem, acc);
  int lane = threadIdx.x & 63, wid = threadIdx.x >> 6;
  int wr = wid >> 2, wcn = wid & 3;
  int rbase = (lane >> 4) * 4, cbase = lane & 15;
  f16* qb = qc + SZ(bhl) * NS * ND;
#pragma unroll
  for (int mi = 0; mi < 8; ++mi)
#pragma unroll
    for (int ni = 0; ni < 4; ++ni) {
      int colg = tn2 * 256 + wcn * 64 + ni * 16 + cbase;
      float bias = Qb[h * ND + colg];
#pragma unroll
      for (int r = 0; r < 4; ++r) {
        int rowg = tm2 * 256 + wr * 128 + mi * 16 + rbase + r;
        qb[SZ(rowg) * ND + colg] = (f16)(acc[mi][ni][r] + bias);
      }
    }
}

// ---- scores 256^2: store E=exp(s - blk_colmax) + per-key stats ----
// sc block index: lg = bhl*4 + tt2*2 + st2; per-block layout:
//   f16x4 at ((wid*8+mi)*4+ni)*64 + lane
__global__ __launch_bounds__(512, 2) void k_scores256(const f16* __restrict__ qc,
                                                      const f16* __restrict__ xh,
                                                      f16* __restrict__ sc,
                                                      float* __restrict__ mp,
                                                      float* __restrict__ zp, int b0) {
  __shared__ f16 smem[65536];
  int n = gridDim.x;
  int lg = xcd_swz(blockIdx.x, n);
  int st2 = lg & 1, tt2 = (lg >> 1) & 1, bhl = lg >> 2;
  int b = b0 + (bhl >> 4);
  f32x4 acc[8][4] = {};
  gemm256_pipe(qc + SZ(bhl) * NS * ND + SZ(st2) * 256 * ND,
               xh + SZ(b) * NS * ND + SZ(tt2) * 256 * ND, ND, ND, smem, acc);
  int tid = threadIdx.x, lane = tid & 63, wid = tid >> 6;
  int wr = wid >> 2, wcn = wid & 3;
  __syncthreads();  // loop done in all waves -> smem reusable as stats buffer
  float* sbuf = (float*)smem;  // [0..511] colmax (wr*256+col), [512..1023] colsum

  // 1) per-wave (128-row) column max
  float mh[4];
#pragma unroll
  for (int ni = 0; ni < 4; ++ni) {
    float m = -1e30f;
#pragma unroll
    for (int mi = 0; mi < 8; ++mi)
#pragma unroll
      for (int r = 0; r < 4; ++r) m = fmaxf(m, acc[mi][ni][r]);
    m = fmaxf(m, __shfl_xor(m, 16));
    m = fmaxf(m, __shfl_xor(m, 32));  // lanes {l,l^16,l^32,l^48} share col
    mh[ni] = m;
  }
  if (lane < 16) {
#pragma unroll
    for (int ni = 0; ni < 4; ++ni)
      sbuf[wr * 256 + wcn * 64 + ni * 16 + lane] = mh[ni];
  }
  __syncthreads();
  // 2) block (256-row) column max
  int cb_ = lane & 15;
  float tmc[4];
#pragma unroll
  for (int ni = 0; ni < 4; ++ni) {
    int col = wcn * 64 + ni * 16 + cb_;
    tmc[ni] = fmaxf(sbuf[col], sbuf[256 + col]);
  }
  // 3) store E and accumulate column sums
  f16x4* scb = (f16x4*)(sc + SZ(lg) * 65536);
  float sm[4] = {0.f, 0.f, 0.f, 0.f};
#pragma unroll
  for (int mi = 0; mi < 8; ++mi)
#pragma unroll
    for (int ni = 0; ni < 4; ++ni) {
      f16x4 o;
#pragma unroll
      for (int r = 0; r < 4; ++r) {
        float ev = __expf(acc[mi][ni][r] - tmc[ni]);
        o[r] = (f16)ev;
        sm[ni] += ev;
      }
      scb[((wid * 8 + mi) * 4 + ni) * 64 + lane] = o;
    }
#pragma unroll
  for (int ni = 0; ni < 4; ++ni) {
    sm[ni] += __shfl_xor(sm[ni], 16);
    sm[ni] += __shfl_xor(sm[ni], 32);
  }
  if (lane < 16) {
#pragma unroll
    for (int ni = 0; ni < 4; ++ni)
      sbuf[512 + wr * 256 + wcn * 64 + ni * 16 + lane] = sm[ni];
  }
  __syncthreads();
  // 4) per-block stats (both wr halves shifted by same tmc -> plain add)
  if (tid < 256) {
    float m  = fmaxf(sbuf[tid], sbuf[256 + tid]);
    float zz = sbuf[512 + tid] + sbuf[768 + tid];
    size_t idx = (SZ(bhl) * 2 + st2) * NS + tt2 * 256 + tid;
    mp[idx] = m; zp[idx] = zz;
  }
}

// ---- combine: per (bhl, t): cs[st2] = exp(mp[st2]-m)/Z ----
__global__ __launch_bounds__(256) void k_stats_combine(const float* __restrict__ mp,
                                                       const float* __restrict__ zp,
                                                       float* __restrict__ cs) {
  int i = blockIdx.x * 256 + threadIdx.x;  // cb*NH*NS
  int bhl = i >> 9, t = i & (NS - 1);
  float m0 = mp[(SZ(bhl) * 2 + 0) * NS + t];
  float m1 = mp[(SZ(bhl) * 2 + 1) * NS + t];
  float m = fmaxf(m0, m1);
  float e0 = __expf(m0 - m), e1 = __expf(m1 - m);
  float Z = zp[(SZ(bhl) * 2 + 0) * NS + t] * e0 + zp[(SZ(bhl) * 2 + 1) * NS + t] * e1;
  float rZ = 1.0f / Z;
  cs[(SZ(bhl) * 2 + 0) * NS + t] = e0 * rZ;
  cs[(SZ(bhl) * 2 + 1) * NS + t] = e1 * rZ;
}

// ---- weight stored E by per-column scale + PV ----
__global__ __launch_bounds__(256) void k_norm_pv(const f16* __restrict__ sc,
                                                 const f16* __restrict__ xvt,
                                                 const float* __restrict__ cs,
                                                 const float* __restrict__ Vb,
                                                 f16* __restrict__ h16, int b0) {
  __shared__ f16 wlds[128 * 128];  // 32 KB, XOR-swizzled
  int bhl = blockIdx.y, b = b0 + (bhl >> 4), h = bhl & 15;
  int st = blockIdx.x;  // 128-row strip 0..3
  int tid = threadIdx.x, lane = tid & 63, wvid = tid >> 6, wr = wvid >> 1, wc = wvid & 1;
  int rbase = (lane >> 4) * 4, cbase = lane & 15, fk = (lane >> 4) * 8;
  f32x4 acc2[2][2] = {};
  const f16* xvh = xvt + SZ(b * NH + h) * NK * NS;
  for (int tt = 0; tt < 4; ++tt) {
    // E source block: producer stored at lg = bhl*4 + tt2*2 + st2
    int blk = (bhl * 2 + (tt >> 1)) * 2 + (st >> 1);
    const f16x4* scb = (const f16x4*)(sc + SZ(blk) * 65536);
    int wave_sc = (st & 1) * 4 + ((tt & 1) * 2 + wc);
#pragma unroll
    for (int ni = 0; ni < 4; ++ni) {
      int tl = wc * 64 + ni * 16 + cbase;
      float csv = cs[(SZ(bhl) * 2 + (st >> 1)) * NS + tt * 128 + tl];
#pragma unroll
      for (int mi = 0; mi < 4; ++mi) {
        int mi_sc = wr * 4 + mi;
        f16x4 v = scb[((wave_sc * 8 + mi_sc) * 4 + ni) * 64 + lane];
#pragma unroll
        for (int r = 0; r < 4; ++r) {
          int sl = wr * 64 + mi * 16 + rbase + r;
          wlds_write(wlds, sl, tl, (f16)((float)v[r] * csv));
        }
      }
    }
    __syncthreads();
    const f16* xvb = xvh + tt * 128;
#pragma unroll
    for (int tc = 0; tc < 4; ++tc) {
      f16x8 aw[2], bx[2];
#pragma unroll
      for (int m2 = 0; m2 < 2; ++m2)
        aw[m2] = wlds_read8(wlds, wvid * 32 + m2 * 16 + cbase, tc * 32 + fk);
#pragma unroll
      for (int n2 = 0; n2 < 2; ++n2)
        bx[n2] = *(const f16x8*)(xvb + SZ(n2 * 16 + cbase) * NS + tc * 32 + fk);
#pragma unroll
      for (int m2 = 0; m2 < 2; ++m2)
#pragma unroll
        for (int n2 = 0; n2 < 2; ++n2)
          acc2[m2][n2] = __builtin_amdgcn_mfma_f32_16x16x32_f16(aw[m2], bx[n2], acc2[m2][n2], 0, 0, 0);
    }
    __syncthreads();
  }
  const float* vb = Vb + h * NK;
#pragma unroll
  for (int m2 = 0; m2 < 2; ++m2)
#pragma unroll
    for (int n2 = 0; n2 < 2; ++n2)
#pragma unroll
      for (int r = 0; r < 4; ++r) {
        int sg = st * 128 + wvid * 32 + m2 * 16 + rbase + r;
        int kk = n2 * 16 + cbase;
        float val = acc2[m2][n2][r] + vb[kk];
        h16[SZ(b * NS + sg) * (NH * NK) + h * NK + kk] = (f16)val;
      }
}

// ---- U = tanh(h @ Wv + bv), stored f16 ----
__global__ __launch_bounds__(256) void k_gemm_u(const f16* __restrict__ h16,
                                                const f16* __restrict__ wvt,
                                                const float* __restrict__ bv,
                                                f16* __restrict__ U) {
  __shared__ f16 smem[128 * 64 * 2];
  int tm = blockIdx.x, tn = blockIdx.y;
  f32x4 acc[4][4] = {};
  gemm_core_128(h16 + SZ(tm) * 128 * ND, wvt + SZ(tn) * 128 * ND, ND, ND, ND / 64, smem, acc);
  int tid = threadIdx.x, lane = tid & 63, wvid = tid >> 6, wr = wvid >> 1, wc = wvid & 1;
  int rbase = (lane >> 4) * 4, cbase = lane & 15;
#pragma unroll
  for (int mi = 0; mi < 4; ++mi)
#pragma unroll
    for (int ni = 0; ni < 4; ++ni) {
      int colg = tn * 128 + wc * 64 + ni * 16 + cbase;
      float bias = bv[colg];
#pragma unroll
      for (int r = 0; r < 4; ++r) {
        int rowg = tm * 128 + wr * 64 + mi * 16 + rbase + r;
        U[SZ(rowg) * NA + colg] = (f16)tanhf(acc[mi][ni][r] + bias);
      }
    }
}

// ---- a = U @ wq + bq (one wave per row) ----
__global__ __launch_bounds__(256) void k_a(const f16* __restrict__ U,
                                           const float* __restrict__ wq,
                                           const float* __restrict__ bq,
                                           float* __restrict__ a) {
  int wid = (blockIdx.x * 256 + threadIdx.x) >> 6;
  int lane = threadIdx.x & 63;
  const f16* u = U + SZ(wid) * NA;
  float p = 0.f;
#pragma unroll
  for (int j = 0; j < NA / 64; ++j) p += (float)u[lane + 64 * j] * wq[lane + 64 * j];
#pragma unroll
  for (int o = 32; o; o >>= 1) p += __shfl_xor(p, o);
  if (lane == 0) a[wid] = p + bq[0];
}

// ---- z partials ----
__global__ __launch_bounds__(256) void k_zpart(const f16* __restrict__ h16,
                                               const float* __restrict__ a,
                                               float* __restrict__ zpt) {
  int b = blockIdx.y, c = blockIdx.x, tid = threadIdx.x;
  float z0 = 0.f, z1 = 0.f;
  for (int s = 0; s < 64; ++s) {
    int sg = c * 64 + s;
    float av = a[b * NS + sg];
    const f16* hr = h16 + SZ(b * NS + sg) * (NH * NK);
    f16x2 v = ((const f16x2*)hr)[tid];
    z0 += av * (float)v[0];
    z1 += av * (float)v[1];
  }
  zpt[SZ(b * 8 + c) * 512 + 2 * tid]     = z0;
  zpt[SZ(b * 8 + c) * 512 + 2 * tid + 1] = z1;
}

__global__ __launch_bounds__(256) void k_zred(const float* __restrict__ zpt,
                                              float* __restrict__ out) {
  int i = blockIdx.x * 256 + threadIdx.x;  // NB*512
  int b = i >> 9, k = i & 511;
  float z = 0.f;
#pragma unroll
  for (int c = 0; c < 8; ++c) z += zpt[SZ(b * 8 + c) * 512 + k];
  out[i] = z;
}

// ---- workspace layout as a function of chunk size cb ----
static size_t ws_plan(int cb, size_t off[14]) {
  size_t o = 0;
  auto put = [&](size_t bytes) { size_t r = o; o += (bytes + 255) & ~SZ(255); return r; };
  off[0]  = put(SZ(NB) * NS * ND * 2);       // xh
  off[1]  = put(SZ(NH) * ND * ND * 2);       // qwt
  off[2]  = put(SZ(NA) * ND * 2);            // wvt
  off[3]  = put(SZ(NH) * NK * ND * 2);       // vwt
  off[4]  = put(SZ(NB) * NH * NK * NS * 2);  // xvt
  off[5]  = put(SZ(cb) * NH * NS * ND * 2);  // qc
  off[6]  = put(SZ(cb) * NH * NS * NS * 2);  // sc (E values, frag-blocked)
  off[7]  = put(SZ(cb) * NH * 2 * NS * 4);   // mp
  off[8]  = put(SZ(cb) * NH * 2 * NS * 4);   // zps
  off[9]  = put(SZ(cb) * NH * 2 * NS * 4);   // cs
  off[10] = put(SZ(NB) * NS * NH * NK * 2);  // h16
  off[11] = put(SZ(NB) * NS * NA * 2);       // U
  off[12] = put(SZ(NB) * NS * 4);            // a
  off[13] = put(SZ(NB) * 8 * NH * NK * 4);   // zpt
  return o;
}

extern "C" void kernel_launch(void* const* d_in, const int* in_sizes, int n_in,
                              void* d_out, int out_size, void* d_ws, size_t ws_size,
                              hipStream_t stream) {
  const float* x  = (const float*)d_in[0];
  const float* Qw = (const float*)d_in[1];
  const float* Qb = (const float*)d_in[2];
  const float* Vw = (const float*)d_in[3];
  const float* Vb = (const float*)d_in[4];
  const float* Wv = (const float*)d_in[5];
  const float* bv = (const float*)d_in[6];
  const float* wq = (const float*)d_in[7];
  const float* bq = (const float*)d_in[8];

  int cbv = 0;
  size_t off[14];
  const int cand[5] = {32, 16, 8, 4, 2};
  for (int ci = 0; ci < 5; ++ci) {
    if (ws_plan(cand[ci], off) <= ws_size) { cbv = cand[ci]; break; }
  }
  if (cbv == 0) return;

  char* ws = (char*)d_ws;
  f16*   xh   = (f16*)(ws + off[0]);
  f16*   qwt  = (f16*)(ws + off[1]);
  f16*   wvt  = (f16*)(ws + off[2]);
  f16*   vwt  = (f16*)(ws + off[3]);
  f16*   xvt  = (f16*)(ws + off[4]);
  f16*   qc   = (f16*)(ws + off[5]);
  f16*   sc   = (f16*)(ws + off[6]);
  float* mp   = (float*)(ws + off[7]);
  float* zps  = (float*)(ws + off[8]);
  float* cs   = (float*)(ws + off[9]);
  f16*   h16  = (f16*)(ws + off[10]);
  f16*   U    = (f16*)(ws + off[11]);
  float* a    = (float*)(ws + off[12]);
  float* zpt  = (float*)(ws + off[13]);
  float* zout = (float*)d_out;

  // prep
  k_cast4<<<SZ(NB) * NS * ND / 4 / 256, 256, 0, stream>>>(x, xh, NB * NS * ND / 4);
  k_tcast<<<dim3(16, 16, 16), dim3(32, 8), 0, stream>>>(Qw, qwt, ND, ND, (long)ND * ND, (long)ND * ND);
  k_tcast<<<dim3(8, 16, 1), dim3(32, 8), 0, stream>>>(Wv, wvt, ND, NA, 0, 0);
  k_tcast<<<dim3(1, 16, 16), dim3(32, 8), 0, stream>>>(Vw, vwt, ND, NK, (long)ND * NK, (long)NK * ND);
  k_gemm_xv<<<dim3(4, 1, NB * 4), 256, 0, stream>>>(xh, vwt, xvt);

  // batch-chunked attention: q -> E+stats -> combine -> weight+PV
  for (int b0 = 0; b0 < NB; b0 += cbv) {
    k_gemm_q256<<<cbv * 64, 512, 0, stream>>>(xh, qwt, Qb, qc, b0);
    k_scores256<<<cbv * 64, 512, 0, stream>>>(qc, xh, sc, mp, zps, b0);
    k_stats_combine<<<cbv * NH * NS / 256, 256, 0, stream>>>(mp, zps, cs);
    k_norm_pv<<<dim3(4, cbv * NH), 256, 0, stream>>>(sc, xvt, cs, Vb, h16, b0);
  }

  // pooling
  k_gemm_u<<<dim3(NB * NS / 128, 2, 1), 256, 0, stream>>>(h16, wvt, bv, U);
  k_a<<<NB * NS / 4, 256, 0, stream>>>(U, wq, bq, a);
  k_zpart<<<dim3(8, NB), 256, 0, stream>>>(h16, a, zpt);
  k_zred<<<NB * 512 / 256, 256, 0, stream>>>(zpt, zout);
}